// Round 9
// baseline (223.480 us; speedup 1.0000x reference)
//
#include <hip/hip_runtime.h>

#define N_NODES 50000
#define N_EDGES 1600000
#define N_TOTAL (N_EDGES + N_NODES)   // edges + self loops
#define F_IN    32
#define HID     64
#define F_OUT   128
#define G       32                    // dst nodes per gather bucket
#define NB      1563                  // ceil(N_NODES / G) gather buckets
#define NBIN    392                   // coarse bins: d >> 7 (4 buckets per bin)
#define CAP1_MAX 5120                 // per-bin cap (mean ~4209 + ~14 sigma)
#define QCAP    1536                  // gather LDS queue cap (mean 1056 + ~15 sigma)
#define OVF_CAP 16384
#define W1WIN   4096                  // pass-1 window (edges per block)
#define NBINBLK  403                  // ceil(N_TOTAL / W1WIN) bin-role blocks
#define NNODEBLK 196                  // node-role blocks (256 nodes each)

// workspace layout (u32 units), ~14.5 MB max:
#define OFF_QBF   0
#define OFF_CUR1  (N_NODES * 32)
#define OFF_OVFC  (OFF_CUR1 + NBIN * 16)
#define OFF_OVF   (OFF_OVFC + 16)
#define OFF_BIN   (OFF_OVF + OVF_CAP)
#define NCLR      (NBIN * 16 + 16)    // words to zero (cur1 + ovfc block)

typedef __attribute__((ext_vector_type(2))) _Float16 h2f;    // packed half2 (1 VGPR)
typedef __attribute__((ext_vector_type(8))) _Float16 half8;  // MFMA f16 frag (4 VGPRs)
typedef __attribute__((ext_vector_type(4))) float v4f;

__device__ __forceinline__ unsigned f2h2(float a, float b) {   // pack 2 f16 (RNE)
    h2f v;
    v.x = (_Float16)a; v.y = (_Float16)b;
    return __builtin_bit_cast(unsigned, v);
}

// relu(a - b) on packed f16 pairs: v_pk_add_f16(neg) + v_pk_max_f16
__device__ __forceinline__ unsigned hsubmax0(unsigned a, unsigned b) {
    h2f x = __builtin_bit_cast(h2f, a) - __builtin_bit_cast(h2f, b);
    h2f z = {(_Float16)0.f, (_Float16)0.f};
    x = __builtin_elementwise_max(x, z);
    return __builtin_bit_cast(unsigned, x);
}

__device__ __forceinline__ float h2lo(unsigned u) { return (float)__builtin_bit_cast(h2f, u).x; }
__device__ __forceinline__ float h2hi(unsigned u) { return (float)__builtin_bit_cast(h2f, u).y; }
__device__ __forceinline__ float f16r(float x)    { return (float)(_Float16)x; }

// Wave-local LDS handoff fence (per-wave staging only; no block barrier).
#define WAVE_FENCE() do { asm volatile("s_waitcnt lgkmcnt(0)" ::: "memory"); \
                          __builtin_amdgcn_sched_barrier(0); } while (0)

// ---------------------------------------------------------------------------
// Kernel Z: zero bin cursors + overflow counter.
// ---------------------------------------------------------------------------
__global__ __launch_bounds__(256) void zero_kernel(unsigned* __restrict__ clr)
{
    const int i = blockIdx.x * 256 + threadIdx.x;
    if (i < NCLR) clr[i] = 0u;
}

// ---------------------------------------------------------------------------
// Kernel AB (fused, block-role split):
//   blocks [0, NBINBLK): pass-1 binning of a 4096-edge window into 392 bins
//     (d>>7, flush runs avg 10.7 entries — the cheap granularity, round-8
//     lesson: 2.6-entry runs at d>>5 cost ~15-20 µs in write amplification).
//     Entry: (d << 16) | s with FULL node id d.
//   blocks [NBINBLK, +NNODEBLK): node precompute Q'[n] (4 lanes/node,
//     acc[16] — the proven VGPR-safe role from rounds 5-8).
// refine is DELETED — the 4-way bucket split moved into gather's compaction.
// ---------------------------------------------------------------------------
__global__ __launch_bounds__(1024) void bin_pre_kernel(
    const int* __restrict__ ei,
    unsigned* __restrict__ cur1, unsigned* __restrict__ bin1,
    unsigned* __restrict__ ovfc, unsigned* __restrict__ ovf, int cap1,
    const float* __restrict__ x, const float* __restrict__ pos,
    const float* __restrict__ W1, const float* __restrict__ b1,
    unsigned* __restrict__ qbf)
{
    __shared__ unsigned stage[W1WIN];       // 16 KB
    __shared__ unsigned hist[NBIN], startp[NBIN + 1], gbase[NBIN];
    __shared__ unsigned wpart[16];
    __shared__ float    w1s[35 * HID + HID]; // 9 KB (node role)

    const int t = threadIdx.x, lane = t & 63;

    if (blockIdx.x >= NBINBLK) {
        // ---- node role (verbatim from rounds 5-8) ----
        for (int i = t; i < 35 * HID; i += 1024) w1s[i] = W1[i];
        if (t < HID) w1s[35 * HID + t] = b1[t];
        __syncthreads();

        const int n = (blockIdx.x - NBINBLK) * 256 + (t >> 2);
        const int sub = t & 3;                  // channel quarter [sub*16, +16)
        if (n >= N_NODES) return;

        const float4* x4 = (const float4*)(x + (long long)n * F_IN);
        const float4 xa = x4[sub * 2], xb = x4[sub * 2 + 1];
        const float xv[8] = {xa.x, xa.y, xa.z, xa.w, xb.x, xb.y, xb.z, xb.w};

        float acc[16];
        #pragma unroll
        for (int k = 0; k < 16; ++k) acc[k] = w1s[35 * HID + sub * 16 + k];

        #pragma unroll
        for (int c = 0; c < F_IN; ++c) {
            const float xm = __shfl(xv[c & 7], (lane & 60) | (c >> 3), 64);
            #pragma unroll
            for (int k = 0; k < 16; ++k)
                acc[k] = fmaf(xm, w1s[c * HID + sub * 16 + k], acc[k]);
        }
        #pragma unroll
        for (int a = 0; a < 3; ++a) {
            const float pp = pos[n * 3 + a];
            #pragma unroll
            for (int k = 0; k < 16; ++k)
                acc[k] = fmaf(pp, w1s[(F_IN + a) * HID + sub * 16 + k], acc[k]);
        }

        uint4* o4 = (uint4*)(qbf + (unsigned)n * 32u + (unsigned)sub * 8u);
        o4[0] = make_uint4(f2h2(acc[0], acc[1]),  f2h2(acc[2], acc[3]),
                           f2h2(acc[4], acc[5]),  f2h2(acc[6], acc[7]));
        o4[1] = make_uint4(f2h2(acc[8], acc[9]),  f2h2(acc[10], acc[11]),
                           f2h2(acc[12], acc[13]), f2h2(acc[14], acc[15]));
        return;
    }

    // ---- bin role (round-7 proven structure, d>>7) ----
    const int wbase = blockIdx.x * W1WIN;

    for (int i = t; i < NBIN; i += 1024) hist[i] = 0u;
    __syncthreads();

    unsigned ev[4]; int bv[4]; unsigned rv[4]; bool val[4];
    #pragma unroll
    for (int k = 0; k < 4; ++k) {
        const int idx = wbase + k * 1024 + t;
        val[k] = idx < N_TOTAL;
        if (val[k]) {
            int s, d;
            if (idx < N_EDGES) { s = ei[idx]; d = ei[N_EDGES + idx]; }
            else               { s = d = idx - N_EDGES; }    // self loop
            ev[k] = ((unsigned)d << 16) | (unsigned)s;
            bv[k] = d >> 7;
            rv[k] = atomicAdd(&hist[bv[k]], 1u);
        }
    }
    __syncthreads();

    // parallel exclusive scan of hist[0..NBIN) -> startp
    unsigned hv = 0;
    if (t < NBIN) hv = hist[t];
    unsigned v = hv;
    #pragma unroll
    for (int o = 1; o < 64; o <<= 1) {
        const unsigned u = __shfl_up(v, o, 64);
        if ((t & 63) >= o) v += u;
    }
    if ((t & 63) == 63) wpart[t >> 6] = v;
    __syncthreads();
    if (t == 0) {
        unsigned r = 0;
        #pragma unroll
        for (int i = 0; i < 16; ++i) { const unsigned c2 = wpart[i]; wpart[i] = r; r += c2; }
        startp[NBIN] = r;
    }
    __syncthreads();
    if (t < NBIN) startp[t] = (v - hv) + wpart[t >> 6];
    if (t < NBIN && hv) gbase[t] = atomicAdd(&cur1[t * 16], hv);
    __syncthreads();

    #pragma unroll
    for (int k = 0; k < 4; ++k)
        if (val[k]) stage[startp[bv[k]] + rv[k]] = ev[k];
    __syncthreads();

    const unsigned total = startp[NBIN];
    for (unsigned i = t; i < total; i += 1024u) {
        const unsigned e = stage[i];
        const unsigned b = e >> 23;                 // bin id = d >> 7
        const unsigned gp = gbase[b] + (i - startp[b]);
        if (gp < (unsigned)cap1) bin1[b * (unsigned)cap1 + gp] = e;
        else {
            const unsigned qo = atomicAdd(ovfc, 1u);
            if (qo < OVF_CAP) ovf[qo] = e;
        }
    }
}

// ---------------------------------------------------------------------------
// Kernel C: gather. One block per 32-node bucket. NEW front-end: scan the
// parent 128-node bin (read 4x per bin — L2/L3 absorbs repeats), ballot-
// compact this bucket's entries into a 6 KB LDS queue (order irrelevant:
// max-agg is commutative). Queue overflow (P~0) -> global ovf list, fixed
// by ovf_kernel after gather. Pipeline below the queue is the round-7/8
// proven inner loop (60.7 µs, VGPR 64, no spill), reading pent from LDS.
// ---------------------------------------------------------------------------
__global__ __launch_bounds__(256, 4) void gather_kernel(
    const unsigned* __restrict__ qbf,   // [N,32] packed f16 Q'
    const float* __restrict__ pos,
    const unsigned* __restrict__ cur1,  // bin cursors (counts), stride 16
    const unsigned* __restrict__ bkt,   // bin1
    int cap1,
    unsigned* __restrict__ ovfc, unsigned* __restrict__ ovf,
    const float* __restrict__ W1p,      // W1 rows 32..34, [3, 64]
    const float* __restrict__ W2, const float* __restrict__ b2,
    float* __restrict__ out)
{
    __shared__ unsigned aggs[(G + 1) * HID];  // 8448 B (+1 dump row)
    __shared__ unsigned rlds[G * 32];         // 4 KB: R[dst] f16 pairs, xor-swizzled
    __shared__ unsigned ast[4][64 * 16];      // 16 KB: per-wave A-stage (one k-half)
    __shared__ unsigned queue[QCAP];          // 6 KB: this bucket's entries
    __shared__ unsigned qcnt;

    const int t = threadIdx.x, lane = t & 63, w = t >> 6;
    const int q = lane >> 4, m15 = lane & 15;
    const int b = blockIdx.x;                 // bucket id
    const int bin = b >> 2, sb = b & 3;       // parent bin, sub-bucket
    const unsigned cntb = min(cur1[bin * 16], (unsigned)cap1);
    const unsigned gb = (unsigned)bin * (unsigned)cap1;

    if (t == 0) qcnt = 0u;
    for (int i = t; i < (G + 1) * HID; i += 256) aggs[i] = 0u;
    for (int i = t; i < G * 32; i += 256) {             // R[dl][k] = pos_dl @ W1p
        const int dl = i >> 5, k2 = i & 31;
        const int node = b * G + dl;
        float v0 = 0.f, v1 = 0.f;
        if (node < N_NODES) {
            #pragma unroll
            for (int a = 0; a < 3; ++a) {
                const float pp = pos[node * 3 + a];
                v0 = fmaf(pp, W1p[a * HID + 2 * k2], v0);
                v1 = fmaf(pp, W1p[a * HID + 2 * k2 + 1], v1);
            }
        }
        rlds[(dl << 5) + ((((k2 >> 2) ^ (dl & 7)) << 2) | (k2 & 3))] = f2h2(v0, v1);
    }
    __syncthreads();                          // qcnt=0 visible before atomics

    // ---- ballot-compaction of the parent bin into the LDS queue ----
    {
        const unsigned nit2 = (cntb + 255u) >> 8;
        for (unsigned it = 0; it < nit2; ++it) {
            const unsigned idx = it * 256u + (unsigned)t;
            unsigned e = 0u; bool mine = false;
            if (idx < cntb) {
                e = bkt[gb + idx];
                mine = (((e >> 21) & 3u) == (unsigned)sb);
            }
            const unsigned long long bal = __ballot(mine);
            const unsigned rank =
                (unsigned)__popcll(bal & ((1ull << lane) - 1ull));
            unsigned wb = 0u;
            if (lane == 0 && bal)
                wb = atomicAdd(&qcnt, (unsigned)__popcll(bal));
            wb = __shfl(wb, 0, 64);
            if (mine) {
                const unsigned p = wb + rank;
                if (p < QCAP) queue[p] = e;
                else {                        // insurance path (P ~ 0)
                    const unsigned qo = atomicAdd(ovfc, 1u);
                    if (qo < OVF_CAP) ovf[qo] = e;
                }
            }
        }
    }

    // W2^T B-fragments in registers (validated rounds 6-8).
    half8 bfr[2][2][2];
    #pragma unroll
    for (int h = 0; h < 2; ++h)
        #pragma unroll
        for (int ntl = 0; ntl < 2; ++ntl) {
            const int nn = (2 * h + ntl) * 16 + m15;
            #pragma unroll
            for (int ks = 0; ks < 2; ++ks) {
                half8 vv;
                #pragma unroll
                for (int j = 0; j < 4; ++j) {
                    const int ku = (ks * 4 + q) * 4 + j;    // k-pair index
                    vv[2 * j]     = (_Float16)W2[(2 * ku) * HID + nn];
                    vv[2 * j + 1] = (_Float16)W2[(2 * ku + 1) * HID + nn];
                }
                bfr[h][ntl][ks] = vv;
            }
        }
    float b2v[4];
    #pragma unroll
    for (int nt = 0; nt < 4; ++nt) b2v[nt] = b2[nt * 16 + m15];
    __syncthreads();                          // queue + rlds + aggs ready

    const unsigned cnt = min(qcnt, (unsigned)QCAP);   // >= 32 (self loops)

    unsigned* aw = ast[w];
    const int axw = ((lane >> 1) & 3) << 2;     // write-side chunk xor (u32 units)
    const int axr = ((m15 >> 1) & 3) << 2;      // read-side chunk xor
    const unsigned nit = (cnt + 255u) >> 8;     // block-uniform iteration count

    #pragma unroll 1
    for (unsigned it = 0; it < nit; ++it) {
        const unsigned off = it * 256u + (unsigned)w * 64u;
        const unsigned rem = (off < cnt) ? min(64u, cnt - off) : 0u;
        const unsigned f = off + (unsigned)lane;
        unsigned pent = 0u;
        if (f < cnt) pent = queue[f];
        const int s = (int)(pent & 0xFFFFu), dl = (int)((pent >> 16) & 31u);

        const uint4* qr = (const uint4*)(qbf + (unsigned)s * 32u);
        const int rbase = dl << 5, rx = dl & 7;

        half8 a0[4], a1[4];

        // ---- k-half 0: load qva, compute, stage, read frags ----
        uint4 qva[4];
        #pragma unroll
        for (int i = 0; i < 4; ++i) qva[i] = qr[i];

        uint4 hh0[4];
        #pragma unroll
        for (int j4 = 0; j4 < 4; ++j4) {
            const uint4 r4 = *(const uint4*)(rlds + rbase + ((j4 ^ rx) << 2));
            hh0[j4].x = hsubmax0(qva[j4].x, r4.x);
            hh0[j4].y = hsubmax0(qva[j4].y, r4.y);
            hh0[j4].z = hsubmax0(qva[j4].z, r4.z);
            hh0[j4].w = hsubmax0(qva[j4].w, r4.w);
        }
        // qva dead — issue second-half loads under the fence sequence below.
        uint4 qvb[4];
        #pragma unroll
        for (int i = 0; i < 4; ++i) qvb[i] = qr[i + 4];

        #pragma unroll
        for (int j4 = 0; j4 < 4; ++j4)
            *(uint4*)(aw + (lane << 4) + ((j4 << 2) ^ axw)) = hh0[j4];
        WAVE_FENCE();                   // stage writes -> cross-lane reads
        #pragma unroll
        for (int mt = 0; mt < 4; ++mt)
            a0[mt] = *(const half8*)(
                aw + ((mt * 16 + m15) << 4) + ((q << 2) ^ axr));
        WAVE_FENCE();                   // reads done -> next overwrite ok

        // ---- k-half 1 ----
        #pragma unroll
        for (int j4 = 0; j4 < 4; ++j4) {
            const uint4 r4 = *(const uint4*)(
                rlds + rbase + (((4 + j4) ^ rx) << 2));
            uint4 hh;
            hh.x = hsubmax0(qvb[j4].x, r4.x);
            hh.y = hsubmax0(qvb[j4].y, r4.y);
            hh.z = hsubmax0(qvb[j4].z, r4.z);
            hh.w = hsubmax0(qvb[j4].w, r4.w);
            *(uint4*)(aw + (lane << 4) + ((j4 << 2) ^ axw)) = hh;
        }
        WAVE_FENCE();
        #pragma unroll
        for (int mt = 0; mt < 4; ++mt)
            a1[mt] = *(const half8*)(
                aw + ((mt * 16 + m15) << 4) + ((q << 2) ^ axr));
        WAVE_FENCE();

        // ---- MFMA layer 2 + epilogue, two 32-channel halves ----
        #pragma unroll
        for (int h = 0; h < 2; ++h) {
            v4f c[4][2];
            #pragma unroll
            for (int mt = 0; mt < 4; ++mt)
                #pragma unroll
                for (int ntl = 0; ntl < 2; ++ntl) {
                    const float bb2 = b2v[2 * h + ntl];     // b2 as C-init
                    c[mt][ntl] = (v4f){bb2, bb2, bb2, bb2};
                }
            #pragma unroll
            for (int mt = 0; mt < 4; ++mt)
                #pragma unroll
                for (int ntl = 0; ntl < 2; ++ntl) {
                    c[mt][ntl] = __builtin_amdgcn_mfma_f32_16x16x32_f16(
                        a0[mt], bfr[h][ntl][0], c[mt][ntl], 0, 0, 0);
                    c[mt][ntl] = __builtin_amdgcn_mfma_f32_16x16x32_f16(
                        a1[mt], bfr[h][ntl][1], c[mt][ntl], 0, 0, 0);
                }
            #pragma unroll
            for (int mt = 0; mt < 4; ++mt)
                #pragma unroll
                for (int r = 0; r < 4; ++r) {
                    const int er = mt * 16 + q * 4 + r;
                    const int dv = __shfl(dl, er, 64);      // inline dst-local
                    const int dle = ((unsigned)er < rem) ? dv : G;  // dump row
                    const int ab = (dle << 6) + m15;
                    #pragma unroll
                    for (int ntl = 0; ntl < 2; ++ntl) {
                        const float hv = fmaxf(c[mt][ntl][r], 0.f);
                        atomicMax(&aggs[ab + (2 * h + ntl) * 16],
                                  __float_as_uint(hv));
                    }
                }
        }
    }

    __syncthreads();
    for (int i = t; i < G * HID; i += 256) {
        const int row = i >> 6, ch = i & 63, n = b * G + row;
        if (n < N_NODES)
            out[(long long)n * F_OUT + HID + ch] = __uint_as_float(aggs[i]);
    }
}

// ---------------------------------------------------------------------------
// Kernel D: overflow fixup (~0 edges in practice; correct for any count).
// Handles both bin-cap and gather-queue overflow entries: (d<<16)|s, full d.
// Numerics match the MFMA path: h1 = relu(f16(Q' - f16(R))), W2 in f16.
// ---------------------------------------------------------------------------
__global__ __launch_bounds__(64) void ovf_kernel(
    const unsigned* __restrict__ qbf, const float* __restrict__ pos,
    const unsigned* __restrict__ ovfc, const unsigned* __restrict__ ovf,
    const float* __restrict__ W1p, const float* __restrict__ W2,
    const float* __restrict__ b2, unsigned* __restrict__ aggbits)
{
    const unsigned n = min(*ovfc, (unsigned)OVF_CAP);
    for (unsigned i = blockIdx.x * 64 + threadIdx.x; i < n; i += gridDim.x * 64) {
        const unsigned p = ovf[i];
        const int s = (int)(p & 0xFFFFu), d = (int)(p >> 16);
        float h1[HID];
        #pragma unroll 1
        for (int k = 0; k < HID; ++k) {
            const unsigned u = qbf[s * 32 + (k >> 1)];
            const float qp = (k & 1) ? h2hi(u) : h2lo(u);
            float r = 0.f;
            #pragma unroll 1
            for (int a = 0; a < 3; ++a) r = fmaf(pos[d * 3 + a], W1p[a * HID + k], r);
            h1[k] = fmaxf(f16r(qp - f16r(r)), 0.f);
        }
        unsigned* ap = aggbits + (long long)d * F_OUT + HID;
        #pragma unroll 1
        for (int k = 0; k < HID; ++k) {
            float a2 = b2[k];
            #pragma unroll 1
            for (int j = 0; j < HID; ++j)
                a2 = fmaf(h1[j], f16r(W2[j * HID + k]), a2);
            a2 = fmaxf(a2, 0.f);
            atomicMax(ap + k, __float_as_uint(a2));
        }
    }
}

// ---------------------------------------------------------------------------
// Kernel E: out[n] = agg[n] @ Wg + bg, in place (unchanged).
// ---------------------------------------------------------------------------
__global__ __launch_bounds__(256) void out_gemm_kernel(
    float* __restrict__ out,            // [N_NODES, 128]
    const float* __restrict__ Wg,       // [HID, F_OUT]
    const float* __restrict__ bg)       // [F_OUT]
{
    const int lane = threadIdx.x & 63;
    const int wave = blockIdx.x * (blockDim.x >> 6) + (threadIdx.x >> 6);
    const int nwav = gridDim.x * (blockDim.x >> 6);

    float w1r[HID], w2r[HID];
    #pragma unroll
    for (int j = 0; j < HID; ++j) {
        w1r[j] = Wg[j * F_OUT + lane];
        w2r[j] = Wg[j * F_OUT + 64 + lane];
    }
    const float bga = bg[lane];
    const float bgb = bg[64 + lane];

    for (int n = wave; n < N_NODES; n += nwav) {
        float* row = out + (long long)n * F_OUT;
        const float a = row[64 + lane];
        float y1 = bga, y2 = bgb;
        #pragma unroll
        for (int j = 0; j < HID; ++j) {
            const float aj = __shfl(a, j, 64);
            y1 = fmaf(aj, w1r[j], y1);
            y2 = fmaf(aj, w2r[j], y2);
        }
        row[lane]      = y1;
        row[64 + lane] = y2;
    }
}

extern "C" void kernel_launch(void* const* d_in, const int* in_sizes, int n_in,
                              void* d_out, int out_size, void* d_ws, size_t ws_size,
                              hipStream_t stream) {
    const float* x   = (const float*)d_in[0];
    const float* pos = (const float*)d_in[1];
    const int*   ei  = (const int*)d_in[2];    // harness delivers integers as int32
    const float* W1  = (const float*)d_in[3];
    const float* b1  = (const float*)d_in[4];
    const float* W2  = (const float*)d_in[5];
    const float* b2  = (const float*)d_in[6];
    const float* Wg  = (const float*)d_in[7];
    const float* bg  = (const float*)d_in[8];
    float* out = (float*)d_out;

    unsigned* ws    = (unsigned*)d_ws;
    unsigned* qbf   = ws + OFF_QBF;
    unsigned* cur1  = ws + OFF_CUR1;
    unsigned* ovfc  = ws + OFF_OVFC;
    unsigned* ovf   = ws + OFF_OVF;
    unsigned* bin1  = ws + OFF_BIN;

    // per-bin capacity from available workspace (overflow path correct anyway)
    long long avail = (long long)(ws_size / 4) - OFF_BIN;
    int cap1 = (int)(avail / NBIN);
    if (cap1 > CAP1_MAX) cap1 = CAP1_MAX;
    if (cap1 < 2048) cap1 = 2048;

    zero_kernel<<<(NCLR + 255) / 256, 256, 0, stream>>>(cur1);
    bin_pre_kernel<<<NBINBLK + NNODEBLK, 1024, 0, stream>>>(
        ei, cur1, bin1, ovfc, ovf, cap1, x, pos, W1, b1, qbf);
    gather_kernel<<<NB, 256, 0, stream>>>(
        qbf, pos, cur1, bin1, cap1, ovfc, ovf,
        W1 + F_IN * HID, W2, b2, out);
    ovf_kernel<<<32, 64, 0, stream>>>(
        qbf, pos, ovfc, ovf, W1 + F_IN * HID, W2, b2, (unsigned*)out);
    out_gemm_kernel<<<512, 256, 0, stream>>>(out, Wg, bg);
}

// Round 10
// 186.409 us; speedup vs baseline: 1.1989x; 1.1989x over previous
//
#include <hip/hip_runtime.h>

#define N_NODES 50000
#define N_EDGES 1600000
#define N_TOTAL (N_EDGES + N_NODES)   // edges + self loops
#define F_IN    32
#define HID     64
#define F_OUT   128
#define G       32                    // dst nodes per gather bucket
#define NB      1563                  // ceil(N_NODES / G)
#define NBIN    392                   // coarse bins: d >> 7 (4 buckets per bin)
#define CAP1_MAX 5120                 // per-bin cap (mean ~4209 + ~14 sigma)
#define OVF_CAP 16384
#define W1WIN   4096                  // pass-1 window (edges per block)
#define NNODEBLK 196                  // node-role blocks in refine_pre (256 nodes each)

// workspace layout (u32 units), ~14.5 MB max (round-7 proven):
#define OFF_QBF   0
#define OFF_CUR1  (N_NODES * 32)
#define OFF_OVFC  (OFF_CUR1 + NBIN * 16)
#define OFF_CELLB (OFF_OVFC + 16)
#define OFF_CELLC (OFF_CELLB + NB)
#define OFF_OVF   (OFF_CELLC + NB + 2)
#define OFF_BIN   (OFF_OVF + OVF_CAP)
#define NCLR      (NBIN * 16 + 16)    // words to zero (cur1 + ovfc block)

typedef __attribute__((ext_vector_type(2))) _Float16 h2f;    // packed half2 (1 VGPR)
typedef __attribute__((ext_vector_type(8))) _Float16 half8;  // MFMA f16 frag (4 VGPRs)
typedef __attribute__((ext_vector_type(4))) float v4f;

__device__ __forceinline__ unsigned f2h2(float a, float b) {   // pack 2 f16 (RNE)
    h2f v;
    v.x = (_Float16)a; v.y = (_Float16)b;
    return __builtin_bit_cast(unsigned, v);
}

// relu(a - b) on packed f16 pairs: v_pk_add_f16(neg) + v_pk_max_f16
__device__ __forceinline__ unsigned hsubmax0(unsigned a, unsigned b) {
    h2f x = __builtin_bit_cast(h2f, a) - __builtin_bit_cast(h2f, b);
    h2f z = {(_Float16)0.f, (_Float16)0.f};
    x = __builtin_elementwise_max(x, z);
    return __builtin_bit_cast(unsigned, x);
}

// Wave-local LDS handoff fence (per-wave staging only; no block barrier).
#define WAVE_FENCE() do { asm volatile("s_waitcnt lgkmcnt(0)" ::: "memory"); \
                          __builtin_amdgcn_sched_barrier(0); } while (0)

// ---------------------------------------------------------------------------
// Kernel Z: zero bin cursors + overflow counter.
// ---------------------------------------------------------------------------
__global__ __launch_bounds__(256) void zero_kernel(unsigned* __restrict__ clr)
{
    const int i = blockIdx.x * 256 + threadIdx.x;
    if (i < NCLR) clr[i] = 0u;
}

// ---------------------------------------------------------------------------
// Kernel B1: pass-1 binning into 392 bins (d>>7). Entry: (d << 16) | s.
// Round-7 proven structure (shfl wave-scan, bin id recomputed e>>23).
// ---------------------------------------------------------------------------
__global__ __launch_bounds__(1024) void bin_kernel(
    const int* __restrict__ ei, unsigned* __restrict__ cur1,
    unsigned* __restrict__ bin1, unsigned* __restrict__ ovfc,
    unsigned* __restrict__ ovf, int cap1)
{
    __shared__ unsigned stage[W1WIN];       // 16 KB
    __shared__ unsigned hist[NBIN], startp[NBIN + 1], gbase[NBIN];
    __shared__ unsigned wpart[16];

    const int t = threadIdx.x;
    const int wbase = blockIdx.x * W1WIN;

    for (int i = t; i < NBIN; i += 1024) hist[i] = 0u;
    __syncthreads();

    unsigned ev[4]; int bv[4]; unsigned rv[4]; bool val[4];
    #pragma unroll
    for (int k = 0; k < 4; ++k) {
        const int idx = wbase + k * 1024 + t;
        val[k] = idx < N_TOTAL;
        if (val[k]) {
            int s, d;
            if (idx < N_EDGES) { s = ei[idx]; d = ei[N_EDGES + idx]; }
            else               { s = d = idx - N_EDGES; }    // self loop
            ev[k] = ((unsigned)d << 16) | (unsigned)s;
            bv[k] = d >> 7;
            rv[k] = atomicAdd(&hist[bv[k]], 1u);
        }
    }
    __syncthreads();

    // parallel exclusive scan of hist[0..NBIN) -> startp
    unsigned hv = 0;
    if (t < NBIN) hv = hist[t];
    unsigned v = hv;
    #pragma unroll
    for (int o = 1; o < 64; o <<= 1) {
        const unsigned u = __shfl_up(v, o, 64);
        if ((t & 63) >= o) v += u;
    }
    if ((t & 63) == 63) wpart[t >> 6] = v;
    __syncthreads();
    if (t == 0) {
        unsigned r = 0;
        #pragma unroll
        for (int i = 0; i < 16; ++i) { const unsigned c2 = wpart[i]; wpart[i] = r; r += c2; }
        startp[NBIN] = r;
    }
    __syncthreads();
    if (t < NBIN) startp[t] = (v - hv) + wpart[t >> 6];
    if (t < NBIN && hv) gbase[t] = atomicAdd(&cur1[t * 16], hv);
    __syncthreads();

    #pragma unroll
    for (int k = 0; k < 4; ++k)
        if (val[k]) stage[startp[bv[k]] + rv[k]] = ev[k];
    __syncthreads();

    const unsigned total = startp[NBIN];
    for (unsigned i = t; i < total; i += 1024u) {
        const unsigned e = stage[i];
        const unsigned b = e >> 23;                 // bin id recomputed
        const unsigned gp = gbase[b] + (i - startp[b]);
        if (gp < (unsigned)cap1) bin1[b * (unsigned)cap1 + gp] = e;
        else {
            const unsigned qo = atomicAdd(ovfc, 1u);
            if (qo < OVF_CAP) ovf[qo] = e;
        }
    }
}

// ---------------------------------------------------------------------------
// Kernel B2+A (fused, block-role split): refine (blocks < NBIN) + node
// precompute (blocks >= NBIN). Round-7 verbatim.
// Refine output entry: (dloc5 << 16) | s.
// ---------------------------------------------------------------------------
__global__ __launch_bounds__(1024) void refine_pre_kernel(
    unsigned* __restrict__ bin1, const unsigned* __restrict__ cur1,
    unsigned* __restrict__ cellbase, unsigned* __restrict__ cellcnt, int cap1,
    const float* __restrict__ x, const float* __restrict__ pos,
    const float* __restrict__ W1, const float* __restrict__ b1,
    unsigned* __restrict__ qbf)
{
    __shared__ unsigned ebuf[CAP1_MAX];     // 20 KB
    __shared__ unsigned ebuf2[CAP1_MAX];    // 20 KB
    __shared__ unsigned cnt32[4 * 32];      // [fb][rep]
    __shared__ unsigned startp[5];
    __shared__ unsigned ssum;
    __shared__ float    w1s[35 * HID + HID]; // 9 KB: W1 rows + b1 (node role)

    const int t = threadIdx.x;

    if (blockIdx.x >= NBIN) {
        // ---- node role ----
        for (int i = t; i < 35 * HID; i += 1024) w1s[i] = W1[i];
        if (t < HID) w1s[35 * HID + t] = b1[t];
        __syncthreads();

        const int n = (blockIdx.x - NBIN) * 256 + (t >> 2);
        const int sub = t & 3;                  // channel quarter [sub*16, +16)
        const int lane = t & 63;
        if (n >= N_NODES) return;

        const float4* x4 = (const float4*)(x + (long long)n * F_IN);
        const float4 xa = x4[sub * 2], xb = x4[sub * 2 + 1];
        const float xv[8] = {xa.x, xa.y, xa.z, xa.w, xb.x, xb.y, xb.z, xb.w};

        float acc[16];
        #pragma unroll
        for (int k = 0; k < 16; ++k) acc[k] = w1s[35 * HID + sub * 16 + k];

        #pragma unroll
        for (int c = 0; c < F_IN; ++c) {
            const float xm = __shfl(xv[c & 7], (lane & 60) | (c >> 3), 64);
            #pragma unroll
            for (int k = 0; k < 16; ++k)
                acc[k] = fmaf(xm, w1s[c * HID + sub * 16 + k], acc[k]);
        }
        #pragma unroll
        for (int a = 0; a < 3; ++a) {
            const float pp = pos[n * 3 + a];
            #pragma unroll
            for (int k = 0; k < 16; ++k)
                acc[k] = fmaf(pp, w1s[(F_IN + a) * HID + sub * 16 + k], acc[k]);
        }

        uint4* o4 = (uint4*)(qbf + (unsigned)n * 32u + (unsigned)sub * 8u);
        o4[0] = make_uint4(f2h2(acc[0], acc[1]),  f2h2(acc[2], acc[3]),
                           f2h2(acc[4], acc[5]),  f2h2(acc[6], acc[7]));
        o4[1] = make_uint4(f2h2(acc[8], acc[9]),  f2h2(acc[10], acc[11]),
                           f2h2(acc[12], acc[13]), f2h2(acc[14], acc[15]));
        return;
    }

    // ---- refine role ----
    const int bb = blockIdx.x;
    const unsigned n1 = min(cur1[bb * 16], (unsigned)cap1);
    const unsigned base1 = (unsigned)bb * (unsigned)cap1;
    const int rep = t & 31, lane = t & 63;

    if (t < 128) cnt32[t] = 0u;
    __syncthreads();

    for (unsigned i = t; i < n1; i += 1024u) {
        const unsigned e = bin1[base1 + i];
        ebuf[i] = e;
        atomicAdd(&cnt32[(((e >> 21) & 3u) << 5) + rep], 1u);
    }
    __syncthreads();

    // parallel exclusive scan of cnt32[0..127]
    unsigned ow = 0;
    if (t < 128) ow = cnt32[t];
    unsigned v = ow;
    #pragma unroll
    for (int o = 1; o < 64; o <<= 1) {
        const unsigned u = __shfl_up(v, o, 64);
        if (lane >= o) v += u;
    }
    if (t == 63) ssum = v;
    __syncthreads();
    if (t >= 64 && t < 128) v += ssum;
    if (t < 128) {
        cnt32[t] = v - ow;                  // exclusive -> write cursor
        if ((t & 31) == 0) startp[t >> 5] = v - ow;
    }
    if (t == 0) startp[4] = n1;
    __syncthreads();

    if (t < 4) {
        const int cell = bb * 4 + t;
        if (cell < NB) {
            cellbase[cell] = base1 + startp[t];
            cellcnt[cell]  = startp[t + 1] - startp[t];
        }
    }

    for (unsigned i = t; i < n1; i += 1024u) {
        const unsigned e = ebuf[i];
        const unsigned p = atomicAdd(&cnt32[(((e >> 21) & 3u) << 5) + rep], 1u);
        ebuf2[p] = (((e >> 16) & 31u) << 16) | (e & 0xFFFFu);
    }
    __syncthreads();
    for (unsigned i = t; i < n1; i += 1024u) bin1[base1 + i] = ebuf2[i];  // coalesced
}

// ---------------------------------------------------------------------------
// Kernel C: gather — round-7/8 proven inner loop (60.7 µs) + two fusions:
//  (1) ovf entries folded into the main loop range [cnt, cnt+no): per-lane
//      dle_lane masks non-matching entries to the dump row (no==0 normally
//      -> one scalar load of cost). ovf_kernel deleted.
//  (2) out-GEMM epilogue: after the main loop, ast (16 KB) is repurposed for
//      Wg as f16 pairs (w2t-style swizzle); A-frags built from aggs
//      (f32->f16); 8 MFMAs/wave compute out[32][128] = agg@Wg + bg written
//      directly. out_gemm kernel deleted.
// ---------------------------------------------------------------------------
__global__ __launch_bounds__(256, 4) void gather_kernel(
    const unsigned* __restrict__ qbf,   // [N,32] packed f16 Q'
    const float* __restrict__ pos,
    const unsigned* __restrict__ cellbase,
    const unsigned* __restrict__ cellcnt,
    const unsigned* __restrict__ bkt,
    const unsigned* __restrict__ ovfc, const unsigned* __restrict__ ovf,
    const float* __restrict__ W1p,      // W1 rows 32..34, [3, 64]
    const float* __restrict__ W2, const float* __restrict__ b2,
    const float* __restrict__ Wg, const float* __restrict__ bg,
    float* __restrict__ out)
{
    __shared__ unsigned aggs[(G + 1) * HID];  // 8448 B (+1 dump row)
    __shared__ unsigned rlds[G * 32];         // 4 KB: R[dst] f16 pairs, xor-swizzled
    __shared__ unsigned ast[4][64 * 16];      // 16 KB: per-wave A-stage / Wg reuse

    const int t = threadIdx.x, lane = t & 63, w = t >> 6;
    const int q = lane >> 4, m15 = lane & 15;
    const int b = blockIdx.x;
    const unsigned cnt  = cellcnt[b];
    const unsigned base = cellbase[b];
    const unsigned no   = min(*ovfc, (unsigned)OVF_CAP);   // ~0 in practice
    const unsigned tot  = cnt + no;

    for (int i = t; i < (G + 1) * HID; i += 256) aggs[i] = 0u;
    for (int i = t; i < G * 32; i += 256) {             // R[dl][k] = pos_dl @ W1p
        const int dl = i >> 5, k2 = i & 31;
        const int node = b * G + dl;
        float v0 = 0.f, v1 = 0.f;
        if (node < N_NODES) {
            #pragma unroll
            for (int a = 0; a < 3; ++a) {
                const float pp = pos[node * 3 + a];
                v0 = fmaf(pp, W1p[a * HID + 2 * k2], v0);
                v1 = fmaf(pp, W1p[a * HID + 2 * k2 + 1], v1);
            }
        }
        rlds[(dl << 5) + ((((k2 >> 2) ^ (dl & 7)) << 2) | (k2 & 3))] = f2h2(v0, v1);
    }

    // W2^T B-fragments in registers (validated rounds 6-9).
    half8 bfr[2][2][2];
    #pragma unroll
    for (int h = 0; h < 2; ++h)
        #pragma unroll
        for (int ntl = 0; ntl < 2; ++ntl) {
            const int nn = (2 * h + ntl) * 16 + m15;
            #pragma unroll
            for (int ks = 0; ks < 2; ++ks) {
                half8 vv;
                #pragma unroll
                for (int j = 0; j < 4; ++j) {
                    const int ku = (ks * 4 + q) * 4 + j;    // k-pair index
                    vv[2 * j]     = (_Float16)W2[(2 * ku) * HID + nn];
                    vv[2 * j + 1] = (_Float16)W2[(2 * ku + 1) * HID + nn];
                }
                bfr[h][ntl][ks] = vv;
            }
        }
    float b2v[4];
    #pragma unroll
    for (int nt = 0; nt < 4; ++nt) b2v[nt] = b2[nt * 16 + m15];
    __syncthreads();

    unsigned* aw = ast[w];
    const int axw = ((lane >> 1) & 3) << 2;     // write-side chunk xor (u32 units)
    const int axr = ((m15 >> 1) & 3) << 2;      // read-side chunk xor
    const unsigned nit = (tot + 255u) >> 8;     // block-uniform (cnt >= 32)

    #pragma unroll 1
    for (unsigned it = 0; it < nit; ++it) {
        const unsigned off = it * 256u + (unsigned)w * 64u;
        const unsigned f = off + (unsigned)lane;
        int s = 0, dle_lane = G;                // dump row by default
        if (f < cnt) {
            const unsigned p2 = bkt[base + f];  // (dloc5<<16)|s, always this bucket
            s = (int)(p2 & 0xFFFFu); dle_lane = (int)(p2 >> 16);
        } else if (f < tot) {
            const unsigned p2 = ovf[f - cnt];   // (d<<16)|s, full d, any bucket
            s = (int)(p2 & 0xFFFFu);
            if ((p2 >> 21) == (unsigned)b) dle_lane = (int)((p2 >> 16) & 31u);
        }
        const int dl = (dle_lane < G) ? dle_lane : 0;   // rlds row (safe default)

        const uint4* qr = (const uint4*)(qbf + (unsigned)s * 32u);
        const int rbase = dl << 5, rx = dl & 7;

        half8 a0[4], a1[4];

        // ---- k-half 0: load qva, compute, stage, read frags ----
        uint4 qva[4];
        #pragma unroll
        for (int i = 0; i < 4; ++i) qva[i] = qr[i];

        uint4 hh0[4];
        #pragma unroll
        for (int j4 = 0; j4 < 4; ++j4) {
            const uint4 r4 = *(const uint4*)(rlds + rbase + ((j4 ^ rx) << 2));
            hh0[j4].x = hsubmax0(qva[j4].x, r4.x);
            hh0[j4].y = hsubmax0(qva[j4].y, r4.y);
            hh0[j4].z = hsubmax0(qva[j4].z, r4.z);
            hh0[j4].w = hsubmax0(qva[j4].w, r4.w);
        }
        // qva dead — issue second-half loads under the fence sequence below.
        uint4 qvb[4];
        #pragma unroll
        for (int i = 0; i < 4; ++i) qvb[i] = qr[i + 4];

        #pragma unroll
        for (int j4 = 0; j4 < 4; ++j4)
            *(uint4*)(aw + (lane << 4) + ((j4 << 2) ^ axw)) = hh0[j4];
        WAVE_FENCE();                   // stage writes -> cross-lane reads
        #pragma unroll
        for (int mt = 0; mt < 4; ++mt)
            a0[mt] = *(const half8*)(
                aw + ((mt * 16 + m15) << 4) + ((q << 2) ^ axr));
        WAVE_FENCE();                   // reads done -> next overwrite ok

        // ---- k-half 1 ----
        #pragma unroll
        for (int j4 = 0; j4 < 4; ++j4) {
            const uint4 r4 = *(const uint4*)(
                rlds + rbase + (((4 + j4) ^ rx) << 2));
            uint4 hh;
            hh.x = hsubmax0(qvb[j4].x, r4.x);
            hh.y = hsubmax0(qvb[j4].y, r4.y);
            hh.z = hsubmax0(qvb[j4].z, r4.z);
            hh.w = hsubmax0(qvb[j4].w, r4.w);
            *(uint4*)(aw + (lane << 4) + ((j4 << 2) ^ axw)) = hh;
        }
        WAVE_FENCE();
        #pragma unroll
        for (int mt = 0; mt < 4; ++mt)
            a1[mt] = *(const half8*)(
                aw + ((mt * 16 + m15) << 4) + ((q << 2) ^ axr));
        WAVE_FENCE();

        // ---- MFMA layer 2 + epilogue, two 32-channel halves ----
        #pragma unroll
        for (int h = 0; h < 2; ++h) {
            v4f c[4][2];
            #pragma unroll
            for (int mt = 0; mt < 4; ++mt)
                #pragma unroll
                for (int ntl = 0; ntl < 2; ++ntl) {
                    const float bb2 = b2v[2 * h + ntl];     // b2 as C-init
                    c[mt][ntl] = (v4f){bb2, bb2, bb2, bb2};
                }
            #pragma unroll
            for (int mt = 0; mt < 4; ++mt)
                #pragma unroll
                for (int ntl = 0; ntl < 2; ++ntl) {
                    c[mt][ntl] = __builtin_amdgcn_mfma_f32_16x16x32_f16(
                        a0[mt], bfr[h][ntl][0], c[mt][ntl], 0, 0, 0);
                    c[mt][ntl] = __builtin_amdgcn_mfma_f32_16x16x32_f16(
                        a1[mt], bfr[h][ntl][1], c[mt][ntl], 0, 0, 0);
                }
            #pragma unroll
            for (int mt = 0; mt < 4; ++mt)
                #pragma unroll
                for (int r = 0; r < 4; ++r) {
                    const int er = mt * 16 + q * 4 + r;
                    const int dv = __shfl(dle_lane, er, 64);   // dump row if invalid
                    const int ab = (dv << 6) + m15;
                    #pragma unroll
                    for (int ntl = 0; ntl < 2; ++ntl) {
                        const float hv = fmaxf(c[mt][ntl][r], 0.f);
                        atomicMax(&aggs[ab + (2 * h + ntl) * 16],
                                  __float_as_uint(hv));
                    }
                }
        }
    }

    // ================= fused out-GEMM epilogue =================
    __syncthreads();                       // aggs final; ast free for reuse
    unsigned* wg16 = &ast[0][0];           // 16 KB: Wg f16 pairs, xor-swizzled
    for (int i = t; i < 128 * 32; i += 256) {
        const int nn = i >> 5, ku = i & 31;     // k-pair index
        wg16[(nn << 5) + ((((ku >> 2) ^ (nn & 7)) << 2) | (ku & 3))] =
            f2h2(Wg[(2 * ku) * F_OUT + nn], Wg[(2 * ku + 1) * F_OUT + nn]);
    }
    __syncthreads();

    // A-frags from aggs (f32 -> f16): row = mt2*16+m15, k = ks*32 + q*8 + j
    half8 af[2][2];
    #pragma unroll
    for (int mt2 = 0; mt2 < 2; ++mt2)
        #pragma unroll
        for (int ks = 0; ks < 2; ++ks) {
            const unsigned* ap = aggs + (mt2 * 16 + m15) * 64 + ks * 32 + q * 8;
            const uint4 u0 = *(const uint4*)ap;
            const uint4 u1 = *(const uint4*)(ap + 4);
            uint4 pk;
            pk.x = f2h2(__uint_as_float(u0.x), __uint_as_float(u0.y));
            pk.y = f2h2(__uint_as_float(u0.z), __uint_as_float(u0.w));
            pk.z = f2h2(__uint_as_float(u1.x), __uint_as_float(u1.y));
            pk.w = f2h2(__uint_as_float(u1.z), __uint_as_float(u1.w));
            af[mt2][ks] = __builtin_bit_cast(half8, pk);
        }

    // each wave owns output columns [w*32, w*32+32)
    #pragma unroll
    for (int ntl = 0; ntl < 2; ++ntl) {
        const int nn = w * 32 + ntl * 16 + m15;     // 0..127
        const float bgv = bg[nn];
        half8 bf[2];
        #pragma unroll
        for (int ks = 0; ks < 2; ++ks)
            bf[ks] = *(const half8*)(
                wg16 + (nn << 5) + ((((ks * 4 + q) ^ (nn & 7)) << 2)));
        #pragma unroll
        for (int mt2 = 0; mt2 < 2; ++mt2) {
            v4f c = (v4f){bgv, bgv, bgv, bgv};
            c = __builtin_amdgcn_mfma_f32_16x16x32_f16(af[mt2][0], bf[0], c, 0, 0, 0);
            c = __builtin_amdgcn_mfma_f32_16x16x32_f16(af[mt2][1], bf[1], c, 0, 0, 0);
            #pragma unroll
            for (int r = 0; r < 4; ++r) {
                const int n = b * G + mt2 * 16 + q * 4 + r;
                if (n < N_NODES) out[(long long)n * F_OUT + nn] = c[r];
            }
        }
    }
}

extern "C" void kernel_launch(void* const* d_in, const int* in_sizes, int n_in,
                              void* d_out, int out_size, void* d_ws, size_t ws_size,
                              hipStream_t stream) {
    const float* x   = (const float*)d_in[0];
    const float* pos = (const float*)d_in[1];
    const int*   ei  = (const int*)d_in[2];    // harness delivers integers as int32
    const float* W1  = (const float*)d_in[3];
    const float* b1  = (const float*)d_in[4];
    const float* W2  = (const float*)d_in[5];
    const float* b2  = (const float*)d_in[6];
    const float* Wg  = (const float*)d_in[7];
    const float* bg  = (const float*)d_in[8];
    float* out = (float*)d_out;

    unsigned* ws    = (unsigned*)d_ws;
    unsigned* qbf   = ws + OFF_QBF;
    unsigned* cur1  = ws + OFF_CUR1;
    unsigned* ovfc  = ws + OFF_OVFC;
    unsigned* cellb = ws + OFF_CELLB;
    unsigned* cellc = ws + OFF_CELLC;
    unsigned* ovf   = ws + OFF_OVF;
    unsigned* bin1  = ws + OFF_BIN;

    // per-bin capacity from available workspace (overflow path correct anyway)
    long long avail = (long long)(ws_size / 4) - OFF_BIN;
    int cap1 = (int)(avail / NBIN);
    if (cap1 > CAP1_MAX) cap1 = CAP1_MAX;
    if (cap1 < 2048) cap1 = 2048;

    zero_kernel<<<(NCLR + 255) / 256, 256, 0, stream>>>(cur1);
    bin_kernel<<<(N_TOTAL + W1WIN - 1) / W1WIN, 1024, 0, stream>>>(
        ei, cur1, bin1, ovfc, ovf, cap1);
    refine_pre_kernel<<<NBIN + NNODEBLK, 1024, 0, stream>>>(
        bin1, cur1, cellb, cellc, cap1, x, pos, W1, b1, qbf);
    gather_kernel<<<NB, 256, 0, stream>>>(
        qbf, pos, cellb, cellc, bin1, ovfc, ovf,
        W1 + F_IN * HID, W2, b2, Wg, bg, out);
}